// Round 1
// 314.431 us; speedup vs baseline: 1.1421x; 1.1421x over previous
//
#include <hip/hip_runtime.h>

#define NQ 4096
#define NM 8192
#define DK 128
#define DV 512
#define BATCH 2
#define NT (NM / 64)        // 128 m-tiles per batch
#define KTS 8192            // shorts per K tile: 64 rows x 128 dk (tile-linear swizzled)
#define VTILE 16384         // shorts per (b, mtile, dvh) V tile: 256 dv x 64 m

typedef __attribute__((ext_vector_type(8))) short short8;
typedef __attribute__((ext_vector_type(4))) float f32x4;
typedef unsigned short ushort_t;

static __device__ __forceinline__ unsigned short f2bf(float x) {
    union { float f; unsigned int u; } c; c.f = x;
    unsigned int u = c.u;
    return (unsigned short)((u + 0x7FFFu + ((u >> 16) & 1u)) >> 16);
}
static __device__ __forceinline__ float bf2f(unsigned short h) {
    union { unsigned int u; float f; } c; c.u = ((unsigned int)h) << 16;
    return c.f;
}

// ---------------------------------------------------------------------------
// scan: per-batch compaction of mmask (shfl wave scans). Unchanged.
// ---------------------------------------------------------------------------
__global__ __launch_bounds__(1024) void scan_kernel(
    const int* __restrict__ qmask, const int* __restrict__ mmask,
    int* __restrict__ cidx, int* __restrict__ cpos,
    int* __restrict__ cnts, int* __restrict__ qflags) {
    const int b = blockIdx.x;
    const int t = threadIdx.x;
    const int lane = t & 63;
    const int w = t >> 6;
    __shared__ int wsum[16];
    __shared__ int qsh;

    const int* mp = mmask + b * NM;
    const int base = t * 8;
    int val[8];
#pragma unroll
    for (int i = 0; i < 8; ++i) val[i] = (mp[base + i] != 0);
    int c0 = 0;
#pragma unroll
    for (int i = 0; i < 8; ++i) c0 += val[i];

    int c = c0;
#pragma unroll
    for (int off = 1; off < 64; off <<= 1) {
        int n = __shfl_up(c, off, 64);
        if (lane >= off) c += n;
    }
    if (lane == 63) wsum[w] = c;
    if (t == 0) qsh = 0;
    __syncthreads();
    if (t == 0) {
        int s = 0;
#pragma unroll
        for (int i = 0; i < 16; ++i) { s += wsum[i]; wsum[i] = s; }
    }
    __syncthreads();
    const int wbase = (w == 0) ? 0 : wsum[w - 1];
    int run = wbase + (c - c0);
#pragma unroll
    for (int i = 0; i < 8; ++i) {
        int m = base + i;
        cpos[b * NM + m] = run;
        if (val[i]) { cidx[b * NM + run] = m; ++run; }
    }

    int qa = 0;
    for (int i = t; i < NQ; i += 1024) qa |= (qmask[b * NQ + i] != 0);
    if (qa) atomicOr(&qsh, 1);
    __syncthreads();
    if (t == 0) { cnts[b] = wsum[15]; qflags[b] = qsh; }
}

// ---------------------------------------------------------------------------
// prep Q: transpose [B][DK][NQ] fp32 -> [B][q][DK] bf16 hi/lo (dense rows)
// ---------------------------------------------------------------------------
__global__ __launch_bounds__(256) void prep_q_kernel(
    const float* __restrict__ src, ushort_t* __restrict__ hi,
    ushort_t* __restrict__ lo) {
    const int b = blockIdx.z;
    const int d0 = blockIdx.y * 32;
    const int n0 = blockIdx.x * 32;
    __shared__ float t32[32][33];
    for (int l = threadIdx.x; l < 1024; l += 256) {
        int r = l >> 5, c = l & 31;
        t32[r][c] = src[((size_t)b * DK + d0 + r) * NQ + n0 + c];
    }
    __syncthreads();
    for (int l = threadIdx.x; l < 1024; l += 256) {
        int r = l >> 5, c = l & 31;
        float f = t32[c][r];
        unsigned short h = f2bf(f);
        unsigned short lw = f2bf(f - bf2f(h));
        size_t off = ((size_t)b * NQ + n0 + r) * DK + d0 + c;
        hi[off] = h;
        lo[off] = lw;
    }
}

// ---------------------------------------------------------------------------
// prep K: transpose + compacting gather -> tile-linear swizzled image.
// Per 64-row tile (16 KB): [w:4][ks:4][quad:4][col:16] x 8 shorts, so a wave's
// b128 fragment read (w,ks fixed; lane = quad*16+col) is one contiguous 1 KB.
// ---------------------------------------------------------------------------
__global__ __launch_bounds__(256) void prep_k_kernel(
    const float* __restrict__ src, const int* __restrict__ mmask,
    const int* __restrict__ cpos,
    ushort_t* __restrict__ hi, ushort_t* __restrict__ lo) {
    const int b = blockIdx.z;
    const int d0 = blockIdx.y * 32;
    const int n0 = blockIdx.x * 32;
    __shared__ float t32[32][33];
    for (int l = threadIdx.x; l < 1024; l += 256) {
        int r = l >> 5, c = l & 31;
        t32[r][c] = src[((size_t)b * DK + d0 + r) * NM + n0 + c];
    }
    __syncthreads();
    for (int l = threadIdx.x; l < 1024; l += 256) {
        int r = l >> 5, c = l & 31;
        int m = n0 + r;
        if (mmask[b * NM + m] != 0) {
            int pos = cpos[b * NM + m];
            float f = t32[c][r];
            unsigned short h = f2bf(f);
            unsigned short lw = f2bf(f - bf2f(h));
            int d = d0 + c;
            size_t off = ((size_t)(b * NT + (pos >> 6))) * KTS
                       + ((pos >> 4) & 3) * 2048 + (d >> 5) * 512
                       + ((d >> 3) & 3) * 128 + (pos & 15) * 8 + (d & 7);
            hi[off] = h;
            lo[off] = lw;
        }
    }
}

// ---------------------------------------------------------------------------
// prep V: gather + convert -> tile-linear swizzled V image.
// Per (b, mtile, dvh) 32 KB tile: [w:4][vt:4][ks2:2][quad:4][col:16] x 8 shorts
// so each pv b128 V-fragment read is one contiguous 1 KB per wave.
// ---------------------------------------------------------------------------
__global__ __launch_bounds__(256) void prep_v_kernel(
    const float* __restrict__ src, const int* __restrict__ cidx,
    const int* __restrict__ cnts, ushort_t* __restrict__ dst) {
    const int mt = blockIdx.x;
    const int dvb = blockIdx.y;
    const int b = blockIdx.z;
    const int cnt = cnts[b];
    const int tr = threadIdx.x >> 2;
    const int part = threadIdx.x & 3;
    const int dv = dvb * 64 + tr;
    const int dvh = dv >> 8, rr = dv & 255;
    const int wq = rr >> 6, vt = (rr >> 4) & 3, cl = rr & 15;
    const int ks2 = part >> 1, quad0 = (part & 1) * 2;

    const float* row = src + ((size_t)b * DV + dv) * NM;
    const int* cx = cidx + b * NM + mt * 64 + part * 16;
    ushort_t o[16];
#pragma unroll
    for (int i = 0; i < 16; ++i) {
        int m = mt * 64 + part * 16 + i;
        int idx = (m < cnt) ? cx[i] : 0;
        o[i] = (m < cnt) ? f2bf(row[idx]) : (ushort_t)0;
    }
    ushort_t* dp = dst + (((size_t)(b * NT + mt)) * 2 + dvh) * VTILE
                 + wq * 4096 + vt * 1024 + ks2 * 512 + quad0 * 128 + cl * 8;
    *(short8*)dp = *(short8*)&o[0];
    *(short8*)(dp + 128) = *(short8*)&o[8];
}

// ---------------------------------------------------------------------------
// stats: per-(q-tile, m-quarter) softmax stats. Register-K (no LDS staging,
// ZERO barriers in the main loop), 4-way m-split for occupancy.
// grid 1024 = 128 qt x 4 parts x 2 b, 256 thr.
// ---------------------------------------------------------------------------
__global__ __launch_bounds__(256, 3) void stats_kernel(
    const ushort_t* __restrict__ Qhi, const ushort_t* __restrict__ Qlo,
    const ushort_t* __restrict__ Khi, const ushort_t* __restrict__ Klo,
    const int* __restrict__ cnts,
    float* __restrict__ mpart, float* __restrict__ lpart) {
    const int t = threadIdx.x;
    const int lane = t & 63;
    const int w = t >> 6;
    const int quad = lane >> 4;
    const int col = lane & 15;
    const int bid = blockIdx.x;
    const int part = bid & 3;
    const int b = (bid >> 2) & 1;
    const int qb = (bid >> 3) * 32;

    const int cnt = cnts[b];
    const int nit = (cnt + 63) >> 6;
    const int it0 = (nit * part) >> 2;
    const int it1 = (nit * (part + 1)) >> 2;

    __shared__ float red_m[4][32], red_l[4][32];

    short8 qfh[2][4], qfl[2][4];
    {
        const ushort_t* qhp = Qhi + ((size_t)b * NQ + qb) * DK;
        const ushort_t* qlp = Qlo + ((size_t)b * NQ + qb) * DK;
#pragma unroll
        for (int qt = 0; qt < 2; ++qt)
#pragma unroll
            for (int ks = 0; ks < 4; ++ks) {
                size_t off = (size_t)(qt * 16 + col) * DK + ks * 32 + quad * 8;
                qfh[qt][ks] = *(const short8*)(qhp + off);
                qfl[qt][ks] = *(const short8*)(qlp + off);
            }
    }

    const f32x4 zero4 = {0.f, 0.f, 0.f, 0.f};
    float mloc[2] = {-3.0e38f, -3.0e38f};
    float lloc[2] = {0.0f, 0.0f};
    const ushort_t* kh0 = Khi + w * 2048 + lane * 8;
    const ushort_t* kl0 = Klo + w * 2048 + lane * 8;

    for (int it = it0; it < it1; ++it) {
        const size_t tb = ((size_t)(b * NT + it)) * KTS;
        short8 ah[4], al[4];
#pragma unroll
        for (int ks = 0; ks < 4; ++ks) {
            ah[ks] = *(const short8*)(kh0 + tb + ks * 512);
            al[ks] = *(const short8*)(kl0 + tb + ks * 512);
        }
        f32x4 accS[2];
        accS[0] = zero4; accS[1] = zero4;
#pragma unroll
        for (int ks = 0; ks < 4; ++ks) {
            accS[0] = __builtin_amdgcn_mfma_f32_16x16x32_bf16(ah[ks], qfh[0][ks], accS[0], 0, 0, 0);
            accS[1] = __builtin_amdgcn_mfma_f32_16x16x32_bf16(ah[ks], qfh[1][ks], accS[1], 0, 0, 0);
            accS[0] = __builtin_amdgcn_mfma_f32_16x16x32_bf16(ah[ks], qfl[0][ks], accS[0], 0, 0, 0);
            accS[1] = __builtin_amdgcn_mfma_f32_16x16x32_bf16(ah[ks], qfl[1][ks], accS[1], 0, 0, 0);
            accS[0] = __builtin_amdgcn_mfma_f32_16x16x32_bf16(al[ks], qfh[0][ks], accS[0], 0, 0, 0);
            accS[1] = __builtin_amdgcn_mfma_f32_16x16x32_bf16(al[ks], qfh[1][ks], accS[1], 0, 0, 0);
        }
        const int mrow = it * 64 + w * 16 + quad * 4;
#pragma unroll
        for (int qt = 0; qt < 2; ++qt) {
            float s[4];
            float tm = -3.0e38f;
#pragma unroll
            for (int r = 0; r < 4; ++r) {
                s[r] = (mrow + r < cnt) ? accS[qt][r] * 40.0f : -3.0e38f;
                tm = fmaxf(tm, s[r]);
            }
            float mn = fmaxf(mloc[qt], tm);
            float ps = 0.f;
#pragma unroll
            for (int r = 0; r < 4; ++r)
                ps += (mrow + r < cnt) ? __expf(s[r] - mn) : 0.0f;
            lloc[qt] = lloc[qt] * __expf(mloc[qt] - mn) + ps;
            mloc[qt] = mn;
        }
    }

#pragma unroll
    for (int qt = 0; qt < 2; ++qt) {
        float m = mloc[qt], l = lloc[qt];
#pragma unroll
        for (int d = 16; d <= 32; d <<= 1) {
            float mo = __shfl_xor(m, d, 64);
            float lo = __shfl_xor(l, d, 64);
            float M = fmaxf(m, mo);
            l = l * __expf(m - M) + lo * __expf(mo - M);
            m = M;
        }
        if (lane < 16) { red_m[w][qt * 16 + col] = m; red_l[w][qt * 16 + col] = l; }
    }
    __syncthreads();
    if (t < 32) {
        float M = -3.0e38f;
#pragma unroll
        for (int ww = 0; ww < 4; ++ww) M = fmaxf(M, red_m[ww][t]);
        float L = 0.f;
#pragma unroll
        for (int ww = 0; ww < 4; ++ww)
            L += red_l[ww][t] * __expf(red_m[ww][t] - M);
        size_t so = ((size_t)(b * 4 + part)) * NQ + qb + t;
        mpart[so] = M;
        lpart[so] = L;
    }
}

// ---------------------------------------------------------------------------
// finalize: merge 4 stats parts -> global max + gated 1/L per (b,q).
// ---------------------------------------------------------------------------
__global__ __launch_bounds__(256) void finalize_kernel(
    const float* __restrict__ mpart, const float* __restrict__ lpart,
    const int* __restrict__ cnts, const int* __restrict__ qflags,
    const int* __restrict__ qmask, float* __restrict__ gmaxb,
    float* __restrict__ grinv) {
    const int i = blockIdx.x * 256 + threadIdx.x;   // < BATCH*NQ
    const int b = i >> 12;
    const int q = i & (NQ - 1);
    float M = -3.0e38f, L = 0.f;
#pragma unroll
    for (int c = 0; c < 4; ++c) {
        size_t so = ((size_t)(b * 4 + c)) * NQ + q;
        float mc = mpart[so], lc = lpart[so];
        float Mn = fmaxf(M, mc);
        L = L * __expf(M - Mn) + lc * __expf(mc - Mn);
        M = Mn;
    }
    bool valid = (qflags[b] != 0) && (cnts[b] > 0) && (qmask[i] != 0) && (L > 0.f);
    gmaxb[i] = M;
    grinv[i] = valid ? 1.0f / L : 0.0f;
}

// ---------------------------------------------------------------------------
// pv: register-K + register-V (wave-contiguous 1KB b128 loads from swizzled
// images), double-buffered P in LDS -> ONE barrier per iteration, 2-way
// m-split (chunk 0 -> out buffer, chunk 1 -> workspace partial).
// grid 1024 = 128 qt x (2 b x 2 dvh) x 2 chunks, 256 thr.
// ---------------------------------------------------------------------------
__global__ __launch_bounds__(256, 3) void pv_kernel(
    const ushort_t* __restrict__ Qhi, const ushort_t* __restrict__ Qlo,
    const ushort_t* __restrict__ Khi, const ushort_t* __restrict__ Klo,
    const ushort_t* __restrict__ Vimg, const int* __restrict__ cnts,
    const float* __restrict__ gmaxb, float* __restrict__ out0,
    float* __restrict__ out1) {
    const int t = threadIdx.x;
    const int lane = t & 63;
    const int w = t >> 6;
    const int quad = lane >> 4;
    const int col = lane & 15;
    const int bid = blockIdx.x;
    const int chunk = bid & 1;          // low bit: each XCD sees one m-chunk
    const int cmb = (bid >> 1) & 3;
    const int b = cmb >> 1;
    const int dvh = cmb & 1;
    const int qb = (bid >> 3) * 32;

    const int cnt = cnts[b];
    const int nit = (cnt + 63) >> 6;
    const int nh = (nit + 1) >> 1;
    const int it0 = chunk ? nh : 0;
    const int it1 = chunk ? nit : nh;

    __shared__ __align__(16) ushort_t P_s[2][32][68];

    const float gm[2] = {gmaxb[(size_t)b * NQ + qb + col],
                         gmaxb[(size_t)b * NQ + qb + 16 + col]};

    short8 qfh[2][4], qfl[2][4];
    {
        const ushort_t* qhp = Qhi + ((size_t)b * NQ + qb) * DK;
        const ushort_t* qlp = Qlo + ((size_t)b * NQ + qb) * DK;
#pragma unroll
        for (int qt = 0; qt < 2; ++qt)
#pragma unroll
            for (int ks = 0; ks < 4; ++ks) {
                size_t off = (size_t)(qt * 16 + col) * DK + ks * 32 + quad * 8;
                qfh[qt][ks] = *(const short8*)(qhp + off);
                qfl[qt][ks] = *(const short8*)(qlp + off);
            }
    }

    const ushort_t* kh0 = Khi + w * 2048 + lane * 8;
    const ushort_t* kl0 = Klo + w * 2048 + lane * 8;
    const ushort_t* vl0 = Vimg + ((size_t)(b * NT) * 2 + dvh) * VTILE
                        + w * 4096 + lane * 8;

    const f32x4 zero4 = {0.f, 0.f, 0.f, 0.f};
    f32x4 accO[4][2];
#pragma unroll
    for (int vt = 0; vt < 4; ++vt)
#pragma unroll
        for (int qt = 0; qt < 2; ++qt) accO[vt][qt] = zero4;

    for (int it = it0; it < it1; ++it) {
        // ---- K fragments straight to registers (1KB contiguous per read) ----
        const size_t ktb = ((size_t)(b * NT + it)) * KTS;
        short8 ah[4], al[4];
#pragma unroll
        for (int ks = 0; ks < 4; ++ks) {
            ah[ks] = *(const short8*)(kh0 + ktb + ks * 512);
            al[ks] = *(const short8*)(kl0 + ktb + ks * 512);
        }

        // ---- QK ----
        f32x4 accS[2];
        accS[0] = zero4; accS[1] = zero4;
#pragma unroll
        for (int ks = 0; ks < 4; ++ks) {
            accS[0] = __builtin_amdgcn_mfma_f32_16x16x32_bf16(ah[ks], qfh[0][ks], accS[0], 0, 0, 0);
            accS[1] = __builtin_amdgcn_mfma_f32_16x16x32_bf16(ah[ks], qfh[1][ks], accS[1], 0, 0, 0);
            accS[0] = __builtin_amdgcn_mfma_f32_16x16x32_bf16(ah[ks], qfl[0][ks], accS[0], 0, 0, 0);
            accS[1] = __builtin_amdgcn_mfma_f32_16x16x32_bf16(ah[ks], qfl[1][ks], accS[1], 0, 0, 0);
            accS[0] = __builtin_amdgcn_mfma_f32_16x16x32_bf16(al[ks], qfh[0][ks], accS[0], 0, 0, 0);
            accS[1] = __builtin_amdgcn_mfma_f32_16x16x32_bf16(al[ks], qfh[1][ks], accS[1], 0, 0, 0);
        }

        // ---- V fragments to registers (latency covered by P + barrier) ----
        const ushort_t* vp = vl0 + (size_t)it * (2 * VTILE);
        short8 vf[4][2];
#pragma unroll
        for (int vt = 0; vt < 4; ++vt)
#pragma unroll
            for (int k2 = 0; k2 < 2; ++k2)
                vf[vt][k2] = *(const short8*)(vp + vt * 1024 + k2 * 512);

        // ---- P = exp(s - gmax) -> LDS (double-buffered) ----
        const int mrow = it * 64 + w * 16 + quad * 4;
        const int pb = it & 1;
#pragma unroll
        for (int qt = 0; qt < 2; ++qt) {
            float p[4];
#pragma unroll
            for (int r = 0; r < 4; ++r)
                p[r] = (mrow + r < cnt) ? __expf(accS[qt][r] * 40.0f - gm[qt]) : 0.0f;
            ushort4 pk;
            pk.x = f2bf(p[0]); pk.y = f2bf(p[1]);
            pk.z = f2bf(p[2]); pk.w = f2bf(p[3]);
            *(ushort4*)&P_s[pb][qt * 16 + col][w * 16 + quad * 4] = pk;
        }
        __syncthreads();   // the ONLY barrier per iteration: P[pb] ready

        // ---- PV ----
#pragma unroll
        for (int k2 = 0; k2 < 2; ++k2) {
            short8 b0 = *(const short8*)&P_s[pb][col][k2 * 32 + quad * 8];
            short8 b1 = *(const short8*)&P_s[pb][16 + col][k2 * 32 + quad * 8];
#pragma unroll
            for (int vt = 0; vt < 4; ++vt) {
                accO[vt][0] = __builtin_amdgcn_mfma_f32_16x16x32_bf16(vf[vt][k2], b0, accO[vt][0], 0, 0, 0);
                accO[vt][1] = __builtin_amdgcn_mfma_f32_16x16x32_bf16(vf[vt][k2], b1, accO[vt][1], 0, 0, 0);
            }
        }
    }

    // ---- epilogue: raw partial sums (normalization+gating in combine) ----
    float* pbase = chunk ? out1 : out0;
#pragma unroll
    for (int qt = 0; qt < 2; ++qt) {
        const int q = qb + qt * 16 + col;
#pragma unroll
        for (int vt = 0; vt < 4; ++vt)
#pragma unroll
            for (int r = 0; r < 4; ++r) {
                int dv = dvh * 256 + w * 64 + vt * 16 + quad * 4 + r;
                pbase[((size_t)b * DV + dv) * NQ + q] = accO[vt][qt][r];
            }
    }
}

// ---------------------------------------------------------------------------
// combine: out = (p0 + p1) * grinv[b][q]   (p0 aliases out; elementwise safe)
// ---------------------------------------------------------------------------
__global__ __launch_bounds__(256) void combine_kernel(
    const float* p0, const float* __restrict__ p1,
    const float* __restrict__ grinv, float* out) {
    const size_t i = ((size_t)blockIdx.x * 256 + threadIdx.x) * 4;
    f32x4 a = *(const f32x4*)(p0 + i);
    f32x4 c = *(const f32x4*)(p1 + i);
    const int b = (int)(i >> 21);          // DV*NQ = 2^21
    const int q = (int)(i & (NQ - 1));
    f32x4 g = *(const f32x4*)(grinv + (size_t)b * NQ + q);
    f32x4 r = (a + c) * g;
    *(f32x4*)(out + i) = r;
}

// ---------------------------------------------------------------------------
extern "C" void kernel_launch(void* const* d_in, const int* in_sizes, int n_in,
                              void* d_out, int out_size, void* d_ws, size_t ws_size,
                              hipStream_t stream) {
    const float* qkey  = (const float*)d_in[0];
    // d_in[1] (qval) unused by the reference
    const int*   qmask = (const int*)d_in[2];
    const float* mkey  = (const float*)d_in[3];
    const float* mval  = (const float*)d_in[4];
    const int*   mmask = (const int*)d_in[5];
    float* out = (float*)d_out;

    char* ws = (char*)d_ws;
    size_t off = 0;
    const size_t QS  = (size_t)BATCH * NQ * DK * 2;          // 2 MB each
    const size_t KS2 = (size_t)BATCH * NM * DK * 2;          // 4 MB each (swizzled)
    const size_t VS  = (size_t)BATCH * NT * 2 * VTILE * 2;   // 16 MB
    const size_t OS  = (size_t)BATCH * DV * NQ * 4;          // 16.8 MB
    ushort_t* Qhi = (ushort_t*)(ws + off); off += QS;
    ushort_t* Qlo = (ushort_t*)(ws + off); off += QS;
    ushort_t* Khi = (ushort_t*)(ws + off); off += KS2;
    ushort_t* Klo = (ushort_t*)(ws + off); off += KS2;
    ushort_t* Vc  = (ushort_t*)(ws + off); off += VS;
    float* part1  = (float*)(ws + off); off += OS;           // chunk-1 partial
    float* mpart  = (float*)(ws + off); off += (size_t)BATCH * 4 * NQ * 4;
    float* lpart  = (float*)(ws + off); off += (size_t)BATCH * 4 * NQ * 4;
    float* gmaxb  = (float*)(ws + off); off += (size_t)BATCH * NQ * 4;
    float* grinv  = (float*)(ws + off); off += (size_t)BATCH * NQ * 4;
    int* cidx     = (int*)(ws + off); off += (size_t)BATCH * NM * 4;
    int* cpos     = (int*)(ws + off); off += (size_t)BATCH * NM * 4;
    int* cnts     = (int*)(ws + off); off += 64;
    int* qflags   = (int*)(ws + off); off += 64;

    scan_kernel<<<BATCH, 1024, 0, stream>>>(qmask, mmask, cidx, cpos, cnts, qflags);

    dim3 gq(NQ / 32, DK / 32, BATCH);
    prep_q_kernel<<<gq, 256, 0, stream>>>(qkey, Qhi, Qlo);
    dim3 gk(NM / 32, DK / 32, BATCH);
    prep_k_kernel<<<gk, 256, 0, stream>>>(mkey, mmask, cpos, Khi, Klo);
    dim3 gv(NM / 64, DV / 64, BATCH);
    prep_v_kernel<<<gv, 256, 0, stream>>>(mval, cidx, cnts, Vc);

    stats_kernel<<<(NQ / 32) * 8, 256, 0, stream>>>(
        Qhi, Qlo, Khi, Klo, cnts, mpart, lpart);
    finalize_kernel<<<(BATCH * NQ) / 256, 256, 0, stream>>>(
        mpart, lpart, cnts, qflags, qmask, gmaxb, grinv);

    pv_kernel<<<(NQ / 32) * 8, 256, 0, stream>>>(
        Qhi, Qlo, Khi, Klo, Vc, cnts, gmaxb, out, part1);

    combine_kernel<<<(int)((size_t)BATCH * DV * NQ / 1024), 256, 0, stream>>>(
        out, part1, grinv, out);
}

// Round 2
// 302.268 us; speedup vs baseline: 1.1881x; 1.0402x over previous
//
#include <hip/hip_runtime.h>

#define NQ 4096
#define NM 8192
#define DK 128
#define DV 512
#define BATCH 2
#define NT (NM / 64)        // 128 m-tiles per batch
#define KTS 8192            // shorts per K tile: 64 rows x 128 dk (tile-linear swizzled)
#define VTILE 16384         // shorts per (b, mtile, dvh) V tile: 256 dv x 64 m

typedef __attribute__((ext_vector_type(8))) short short8;
typedef __attribute__((ext_vector_type(4))) float f32x4;
typedef unsigned short ushort_t;

static __device__ __forceinline__ unsigned short f2bf(float x) {
    union { float f; unsigned int u; } c; c.f = x;
    unsigned int u = c.u;
    return (unsigned short)((u + 0x7FFFu + ((u >> 16) & 1u)) >> 16);
}
static __device__ __forceinline__ float bf2f(unsigned short h) {
    union { unsigned int u; float f; } c; c.u = ((unsigned int)h) << 16;
    return c.f;
}

// K-tile register fragment load (1KB contiguous per wave per b128)
#define LOADK(AH, AL, itn_) do {                                              \
    const size_t ktb_ = kbase + (size_t)(itn_) * KTS;                         \
    _Pragma("unroll")                                                         \
    for (int ks_ = 0; ks_ < 4; ++ks_) {                                       \
        AH[ks_] = *(const short8*)(kh0 + ktb_ + ks_ * 512);                   \
        AL[ks_] = *(const short8*)(kl0 + ktb_ + ks_ * 512);                   \
    }                                                                         \
} while (0)

// ---------------------------------------------------------------------------
// scan: per-batch compaction of mmask (shfl wave scans). Unchanged.
// ---------------------------------------------------------------------------
__global__ __launch_bounds__(1024) void scan_kernel(
    const int* __restrict__ qmask, const int* __restrict__ mmask,
    int* __restrict__ cidx, int* __restrict__ cpos,
    int* __restrict__ cnts, int* __restrict__ qflags) {
    const int b = blockIdx.x;
    const int t = threadIdx.x;
    const int lane = t & 63;
    const int w = t >> 6;
    __shared__ int wsum[16];
    __shared__ int qsh;

    const int* mp = mmask + b * NM;
    const int base = t * 8;
    int val[8];
#pragma unroll
    for (int i = 0; i < 8; ++i) val[i] = (mp[base + i] != 0);
    int c0 = 0;
#pragma unroll
    for (int i = 0; i < 8; ++i) c0 += val[i];

    int c = c0;
#pragma unroll
    for (int off = 1; off < 64; off <<= 1) {
        int n = __shfl_up(c, off, 64);
        if (lane >= off) c += n;
    }
    if (lane == 63) wsum[w] = c;
    if (t == 0) qsh = 0;
    __syncthreads();
    if (t == 0) {
        int s = 0;
#pragma unroll
        for (int i = 0; i < 16; ++i) { s += wsum[i]; wsum[i] = s; }
    }
    __syncthreads();
    const int wbase = (w == 0) ? 0 : wsum[w - 1];
    int run = wbase + (c - c0);
#pragma unroll
    for (int i = 0; i < 8; ++i) {
        int m = base + i;
        cpos[b * NM + m] = run;
        if (val[i]) { cidx[b * NM + run] = m; ++run; }
    }

    int qa = 0;
    for (int i = t; i < NQ; i += 1024) qa |= (qmask[b * NQ + i] != 0);
    if (qa) atomicOr(&qsh, 1);
    __syncthreads();
    if (t == 0) { cnts[b] = wsum[15]; qflags[b] = qsh; }
}

// ---------------------------------------------------------------------------
// prep Q: transpose [B][DK][NQ] fp32 -> [B][q][DK] bf16 hi/lo (dense rows)
// ---------------------------------------------------------------------------
__global__ __launch_bounds__(256) void prep_q_kernel(
    const float* __restrict__ src, ushort_t* __restrict__ hi,
    ushort_t* __restrict__ lo) {
    const int b = blockIdx.z;
    const int d0 = blockIdx.y * 32;
    const int n0 = blockIdx.x * 32;
    __shared__ float t32[32][33];
    for (int l = threadIdx.x; l < 1024; l += 256) {
        int r = l >> 5, c = l & 31;
        t32[r][c] = src[((size_t)b * DK + d0 + r) * NQ + n0 + c];
    }
    __syncthreads();
    for (int l = threadIdx.x; l < 1024; l += 256) {
        int r = l >> 5, c = l & 31;
        float f = t32[c][r];
        unsigned short h = f2bf(f);
        unsigned short lw = f2bf(f - bf2f(h));
        size_t off = ((size_t)b * NQ + n0 + r) * DK + d0 + c;
        hi[off] = h;
        lo[off] = lw;
    }
}

// ---------------------------------------------------------------------------
// prep K: transpose + compacting gather -> tile-linear swizzled image.
// Per 64-row tile (16 KB): [w:4][ks:4][quad:4][col:16] x 8 shorts, so a wave's
// b128 fragment read (w,ks fixed; lane = quad*16+col) is one contiguous 1 KB.
// ---------------------------------------------------------------------------
__global__ __launch_bounds__(256) void prep_k_kernel(
    const float* __restrict__ src, const int* __restrict__ mmask,
    const int* __restrict__ cpos,
    ushort_t* __restrict__ hi, ushort_t* __restrict__ lo) {
    const int b = blockIdx.z;
    const int d0 = blockIdx.y * 32;
    const int n0 = blockIdx.x * 32;
    __shared__ float t32[32][33];
    for (int l = threadIdx.x; l < 1024; l += 256) {
        int r = l >> 5, c = l & 31;
        t32[r][c] = src[((size_t)b * DK + d0 + r) * NM + n0 + c];
    }
    __syncthreads();
    for (int l = threadIdx.x; l < 1024; l += 256) {
        int r = l >> 5, c = l & 31;
        int m = n0 + r;
        if (mmask[b * NM + m] != 0) {
            int pos = cpos[b * NM + m];
            float f = t32[c][r];
            unsigned short h = f2bf(f);
            unsigned short lw = f2bf(f - bf2f(h));
            int d = d0 + c;
            size_t off = ((size_t)(b * NT + (pos >> 6))) * KTS
                       + ((pos >> 4) & 3) * 2048 + (d >> 5) * 512
                       + ((d >> 3) & 3) * 128 + (pos & 15) * 8 + (d & 7);
            hi[off] = h;
            lo[off] = lw;
        }
    }
}

// ---------------------------------------------------------------------------
// prep V: gather + convert -> tile-linear swizzled V image.
// Per (b, mtile, dvh) 32 KB tile: [w:4][vt:4][ks2:2][quad:4][col:16] x 8 shorts
// so each pv b128 V-fragment read is one contiguous 1 KB per wave.
// ---------------------------------------------------------------------------
__global__ __launch_bounds__(256) void prep_v_kernel(
    const float* __restrict__ src, const int* __restrict__ cidx,
    const int* __restrict__ cnts, ushort_t* __restrict__ dst) {
    const int mt = blockIdx.x;
    const int dvb = blockIdx.y;
    const int b = blockIdx.z;
    const int cnt = cnts[b];
    const int tr = threadIdx.x >> 2;
    const int part = threadIdx.x & 3;
    const int dv = dvb * 64 + tr;
    const int dvh = dv >> 8, rr = dv & 255;
    const int wq = rr >> 6, vt = (rr >> 4) & 3, cl = rr & 15;
    const int ks2 = part >> 1, quad0 = (part & 1) * 2;

    const float* row = src + ((size_t)b * DV + dv) * NM;
    const int* cx = cidx + b * NM + mt * 64 + part * 16;
    ushort_t o[16];
#pragma unroll
    for (int i = 0; i < 16; ++i) {
        int m = mt * 64 + part * 16 + i;
        int idx = (m < cnt) ? cx[i] : 0;
        o[i] = (m < cnt) ? f2bf(row[idx]) : (ushort_t)0;
    }
    ushort_t* dp = dst + (((size_t)(b * NT + mt)) * 2 + dvh) * VTILE
                 + wq * 4096 + vt * 1024 + ks2 * 512 + quad0 * 128 + cl * 8;
    *(short8*)dp = *(short8*)&o[0];
    *(short8*)(dp + 128) = *(short8*)&o[8];
}

// ---------------------------------------------------------------------------
// stats: per-(q-tile, m-quarter) softmax stats. Register-K, ZERO barriers,
// explicit A/B K double-buffer prefetch (loads stay in flight a full iter).
// grid 1024 = 128 qt x 4 parts x 2 b, 256 thr.
// ---------------------------------------------------------------------------
__global__ __launch_bounds__(256, 3) void stats_kernel(
    const ushort_t* __restrict__ Qhi, const ushort_t* __restrict__ Qlo,
    const ushort_t* __restrict__ Khi, const ushort_t* __restrict__ Klo,
    const int* __restrict__ cnts,
    float* __restrict__ mpart, float* __restrict__ lpart) {
    const int t = threadIdx.x;
    const int lane = t & 63;
    const int w = t >> 6;
    const int quad = lane >> 4;
    const int col = lane & 15;
    const int bid = blockIdx.x;
    const int part = bid & 3;
    const int b = (bid >> 2) & 1;
    const int qb = (bid >> 3) * 32;

    const int cnt = cnts[b];
    const int nit = (cnt + 63) >> 6;
    const int it0 = (nit * part) >> 2;
    const int it1 = (nit * (part + 1)) >> 2;

    __shared__ float red_m[4][32], red_l[4][32];

    short8 qfh[2][4], qfl[2][4];
    {
        const ushort_t* qhp = Qhi + ((size_t)b * NQ + qb) * DK;
        const ushort_t* qlp = Qlo + ((size_t)b * NQ + qb) * DK;
#pragma unroll
        for (int qt = 0; qt < 2; ++qt)
#pragma unroll
            for (int ks = 0; ks < 4; ++ks) {
                size_t off = (size_t)(qt * 16 + col) * DK + ks * 32 + quad * 8;
                qfh[qt][ks] = *(const short8*)(qhp + off);
                qfl[qt][ks] = *(const short8*)(qlp + off);
            }
    }

    const f32x4 zero4 = {0.f, 0.f, 0.f, 0.f};
    float mloc[2] = {-3.0e38f, -3.0e38f};
    float lloc[2] = {0.0f, 0.0f};
    const ushort_t* kh0 = Khi + w * 2048 + lane * 8;
    const ushort_t* kl0 = Klo + w * 2048 + lane * 8;
    const size_t kbase = (size_t)(b * NT) * KTS;

#define ST_PHASE(CKH, CKL, NKH, NKL, it_, itn_) do {                          \
    LOADK(NKH, NKL, itn_);                                                    \
    f32x4 aS0 = zero4, aS1 = zero4;                                           \
    _Pragma("unroll")                                                         \
    for (int ks = 0; ks < 4; ++ks) {                                          \
        aS0 = __builtin_amdgcn_mfma_f32_16x16x32_bf16(CKH[ks], qfh[0][ks], aS0, 0, 0, 0); \
        aS1 = __builtin_amdgcn_mfma_f32_16x16x32_bf16(CKH[ks], qfh[1][ks], aS1, 0, 0, 0); \
        aS0 = __builtin_amdgcn_mfma_f32_16x16x32_bf16(CKH[ks], qfl[0][ks], aS0, 0, 0, 0); \
        aS1 = __builtin_amdgcn_mfma_f32_16x16x32_bf16(CKH[ks], qfl[1][ks], aS1, 0, 0, 0); \
        aS0 = __builtin_amdgcn_mfma_f32_16x16x32_bf16(CKL[ks], qfh[0][ks], aS0, 0, 0, 0); \
        aS1 = __builtin_amdgcn_mfma_f32_16x16x32_bf16(CKL[ks], qfh[1][ks], aS1, 0, 0, 0); \
    }                                                                         \
    const int mrow_ = (it_) * 64 + w * 16 + quad * 4;                         \
    _Pragma("unroll")                                                         \
    for (int qt = 0; qt < 2; ++qt) {                                          \
        const f32x4& aS = (qt == 0) ? aS0 : aS1;                              \
        float s[4];                                                           \
        float tm = -3.0e38f;                                                  \
        _Pragma("unroll")                                                     \
        for (int r = 0; r < 4; ++r) {                                         \
            s[r] = (mrow_ + r < cnt) ? aS[r] * 40.0f : -3.0e38f;              \
            tm = fmaxf(tm, s[r]);                                             \
        }                                                                     \
        float mn = fmaxf(mloc[qt], tm);                                       \
        float ps = 0.f;                                                       \
        _Pragma("unroll")                                                     \
        for (int r = 0; r < 4; ++r)                                           \
            ps += (mrow_ + r < cnt) ? __expf(s[r] - mn) : 0.0f;               \
        lloc[qt] = lloc[qt] * __expf(mloc[qt] - mn) + ps;                     \
        mloc[qt] = mn;                                                        \
    }                                                                         \
} while (0)

    short8 kAh[4], kAl[4], kBh[4], kBl[4];
    int it = it0;
    if (it < it1) {
        LOADK(kAh, kAl, it);
        int itn;
        while (true) {
            itn = (it + 1 < it1) ? it + 1 : it;
            ST_PHASE(kAh, kAl, kBh, kBl, it, itn);
            if (++it >= it1) break;
            itn = (it + 1 < it1) ? it + 1 : it;
            ST_PHASE(kBh, kBl, kAh, kAl, it, itn);
            if (++it >= it1) break;
        }
    }
#undef ST_PHASE

#pragma unroll
    for (int qt = 0; qt < 2; ++qt) {
        float m = mloc[qt], l = lloc[qt];
#pragma unroll
        for (int d = 16; d <= 32; d <<= 1) {
            float mo = __shfl_xor(m, d, 64);
            float lo = __shfl_xor(l, d, 64);
            float M = fmaxf(m, mo);
            l = l * __expf(m - M) + lo * __expf(mo - M);
            m = M;
        }
        if (lane < 16) { red_m[w][qt * 16 + col] = m; red_l[w][qt * 16 + col] = l; }
    }
    __syncthreads();
    if (t < 32) {
        float M = -3.0e38f;
#pragma unroll
        for (int ww = 0; ww < 4; ++ww) M = fmaxf(M, red_m[ww][t]);
        float L = 0.f;
#pragma unroll
        for (int ww = 0; ww < 4; ++ww)
            L += red_l[ww][t] * __expf(red_m[ww][t] - M);
        size_t so = ((size_t)(b * 4 + part)) * NQ + qb + t;
        mpart[so] = M;
        lpart[so] = L;
    }
}

// ---------------------------------------------------------------------------
// finalize: merge 4 stats parts -> global max + gated 1/L per (b,q).
// ---------------------------------------------------------------------------
__global__ __launch_bounds__(256) void finalize_kernel(
    const float* __restrict__ mpart, const float* __restrict__ lpart,
    const int* __restrict__ cnts, const int* __restrict__ qflags,
    const int* __restrict__ qmask, float* __restrict__ gmaxb,
    float* __restrict__ grinv) {
    const int i = blockIdx.x * 256 + threadIdx.x;   // < BATCH*NQ
    const int b = i >> 12;
    const int q = i & (NQ - 1);
    float M = -3.0e38f, L = 0.f;
#pragma unroll
    for (int c = 0; c < 4; ++c) {
        size_t so = ((size_t)(b * 4 + c)) * NQ + q;
        float mc = mpart[so], lc = lpart[so];
        float Mn = fmaxf(M, mc);
        L = L * __expf(M - Mn) + lc * __expf(mc - Mn);
        M = Mn;
    }
    bool valid = (qflags[b] != 0) && (cnts[b] > 0) && (qmask[i] != 0) && (L > 0.f);
    gmaxb[i] = M;
    grinv[i] = valid ? 1.0f / L : 0.0f;
}

// ---------------------------------------------------------------------------
// pv: register K double-buffer prefetch + raw barrier (lgkmcnt-only wait, no
// vmcnt drain -> prefetched loads survive the barrier), double-buffered P in
// LDS, ONE barrier per iter. 2-way m-split: chunk 0 -> out, chunk 1 -> ws.
// grid 1024 = 128 qt x (2 b x 2 dvh) x 2 chunks, 256 thr.
// ---------------------------------------------------------------------------
__global__ __launch_bounds__(256, 2) void pv_kernel(
    const ushort_t* __restrict__ Qhi, const ushort_t* __restrict__ Qlo,
    const ushort_t* __restrict__ Khi, const ushort_t* __restrict__ Klo,
    const ushort_t* __restrict__ Vimg, const int* __restrict__ cnts,
    const float* __restrict__ gmaxb, float* __restrict__ out0,
    float* __restrict__ out1) {
    const int t = threadIdx.x;
    const int lane = t & 63;
    const int w = t >> 6;
    const int quad = lane >> 4;
    const int col = lane & 15;
    const int bid = blockIdx.x;
    const int chunk = bid & 1;          // low bits: (chunk,b,dvh) -> XCD-resident
    const int cmb = (bid >> 1) & 3;
    const int b = cmb >> 1;
    const int dvh = cmb & 1;
    const int qb = (bid >> 3) * 32;

    const int cnt = cnts[b];
    const int nit = (cnt + 63) >> 6;
    const int nh = (nit + 1) >> 1;
    const int it0 = chunk ? nh : 0;
    const int it1 = chunk ? nit : nh;

    __shared__ __align__(16) ushort_t P_s[2][32][68];

    const float gm0 = gmaxb[(size_t)b * NQ + qb + col];
    const float gm1 = gmaxb[(size_t)b * NQ + qb + 16 + col];

    short8 qfh[2][4], qfl[2][4];
    {
        const ushort_t* qhp = Qhi + ((size_t)b * NQ + qb) * DK;
        const ushort_t* qlp = Qlo + ((size_t)b * NQ + qb) * DK;
#pragma unroll
        for (int qt = 0; qt < 2; ++qt)
#pragma unroll
            for (int ks = 0; ks < 4; ++ks) {
                size_t off = (size_t)(qt * 16 + col) * DK + ks * 32 + quad * 8;
                qfh[qt][ks] = *(const short8*)(qhp + off);
                qfl[qt][ks] = *(const short8*)(qlp + off);
            }
    }

    const ushort_t* kh0 = Khi + w * 2048 + lane * 8;
    const ushort_t* kl0 = Klo + w * 2048 + lane * 8;
    const size_t kbase = (size_t)(b * NT) * KTS;
    const ushort_t* vl0 = Vimg + ((size_t)(b * NT) * 2 + dvh) * VTILE
                        + w * 4096 + lane * 8;

    const f32x4 zero4 = {0.f, 0.f, 0.f, 0.f};
    f32x4 accO[4][2];
#pragma unroll
    for (int vt = 0; vt < 4; ++vt)
#pragma unroll
        for (int qt = 0; qt < 2; ++qt) accO[vt][qt] = zero4;

// One phase: prefetch next K (reg dbuf), load this iter's V (in flight across
// QK+P+barrier), QK, P -> LDS[PB], lgkmcnt-only wait + raw barrier, PV.
#define PV_PHASE(CKH, CKL, NKH, NKL, PB, it_, itn_) do {                      \
    LOADK(NKH, NKL, itn_);                                                    \
    const ushort_t* vp_ = vl0 + (size_t)(it_) * (2 * VTILE);                  \
    short8 vf_[4][2];                                                         \
    _Pragma("unroll")                                                         \
    for (int vt = 0; vt < 4; ++vt)                                            \
        _Pragma("unroll")                                                     \
        for (int k2 = 0; k2 < 2; ++k2)                                        \
            vf_[vt][k2] = *(const short8*)(vp_ + vt * 1024 + k2 * 512);       \
    f32x4 aS0 = zero4, aS1 = zero4;                                           \
    _Pragma("unroll")                                                         \
    for (int ks = 0; ks < 4; ++ks) {                                          \
        aS0 = __builtin_amdgcn_mfma_f32_16x16x32_bf16(CKH[ks], qfh[0][ks], aS0, 0, 0, 0); \
        aS1 = __builtin_amdgcn_mfma_f32_16x16x32_bf16(CKH[ks], qfh[1][ks], aS1, 0, 0, 0); \
        aS0 = __builtin_amdgcn_mfma_f32_16x16x32_bf16(CKH[ks], qfl[0][ks], aS0, 0, 0, 0); \
        aS1 = __builtin_amdgcn_mfma_f32_16x16x32_bf16(CKH[ks], qfl[1][ks], aS1, 0, 0, 0); \
        aS0 = __builtin_amdgcn_mfma_f32_16x16x32_bf16(CKL[ks], qfh[0][ks], aS0, 0, 0, 0); \
        aS1 = __builtin_amdgcn_mfma_f32_16x16x32_bf16(CKL[ks], qfh[1][ks], aS1, 0, 0, 0); \
    }                                                                         \
    const int mrow_ = (it_) * 64 + w * 16 + quad * 4;                         \
    {                                                                         \
        float p_[4]; ushort4 pk_;                                             \
        _Pragma("unroll")                                                     \
        for (int r = 0; r < 4; ++r)                                           \
            p_[r] = (mrow_ + r < cnt) ? __expf(aS0[r] * 40.0f - gm0) : 0.0f;  \
        pk_.x = f2bf(p_[0]); pk_.y = f2bf(p_[1]);                             \
        pk_.z = f2bf(p_[2]); pk_.w = f2bf(p_[3]);                             \
        *(ushort4*)&P_s[PB][col][w * 16 + quad * 4] = pk_;                    \
        _Pragma("unroll")                                                     \
        for (int r = 0; r < 4; ++r)                                           \
            p_[r] = (mrow_ + r < cnt) ? __expf(aS1[r] * 40.0f - gm1) : 0.0f;  \
        pk_.x = f2bf(p_[0]); pk_.y = f2bf(p_[1]);                             \
        pk_.z = f2bf(p_[2]); pk_.w = f2bf(p_[3]);                             \
        *(ushort4*)&P_s[PB][16 + col][w * 16 + quad * 4] = pk_;               \
    }                                                                         \
    asm volatile("s_waitcnt lgkmcnt(0)" ::: "memory");                        \
    __builtin_amdgcn_s_barrier();                                             \
    __builtin_amdgcn_sched_barrier(0);                                        \
    _Pragma("unroll")                                                         \
    for (int k2 = 0; k2 < 2; ++k2) {                                          \
        short8 pb0_ = *(const short8*)&P_s[PB][col][k2 * 32 + quad * 8];      \
        short8 pb1_ = *(const short8*)&P_s[PB][16 + col][k2 * 32 + quad * 8]; \
        _Pragma("unroll")                                                     \
        for (int vt = 0; vt < 4; ++vt) {                                      \
            accO[vt][0] = __builtin_amdgcn_mfma_f32_16x16x32_bf16(vf_[vt][k2], pb0_, accO[vt][0], 0, 0, 0); \
            accO[vt][1] = __builtin_amdgcn_mfma_f32_16x16x32_bf16(vf_[vt][k2], pb1_, accO[vt][1], 0, 0, 0); \
        }                                                                     \
    }                                                                         \
} while (0)

    short8 kAh[4], kAl[4], kBh[4], kBl[4];
    int it = it0;
    if (it < it1) {
        LOADK(kAh, kAl, it);
        int itn;
        while (true) {
            itn = (it + 1 < it1) ? it + 1 : it;
            PV_PHASE(kAh, kAl, kBh, kBl, 0, it, itn);
            if (++it >= it1) break;
            itn = (it + 1 < it1) ? it + 1 : it;
            PV_PHASE(kBh, kBl, kAh, kAl, 1, it, itn);
            if (++it >= it1) break;
        }
    }
#undef PV_PHASE

    // ---- epilogue: raw partial sums (normalization+gating in combine) ----
    float* pbase = chunk ? out1 : out0;
#pragma unroll
    for (int qt = 0; qt < 2; ++qt) {
        const int q = qb + qt * 16 + col;
#pragma unroll
        for (int vt = 0; vt < 4; ++vt)
#pragma unroll
            for (int r = 0; r < 4; ++r) {
                int dv = dvh * 256 + w * 64 + vt * 16 + quad * 4 + r;
                pbase[((size_t)b * DV + dv) * NQ + q] = accO[vt][qt][r];
            }
    }
}

// ---------------------------------------------------------------------------
// combine: out = (p0 + p1) * grinv[b][q]   (p0 aliases out; elementwise safe)
// ---------------------------------------------------------------------------
__global__ __launch_bounds__(256) void combine_kernel(
    const float* p0, const float* __restrict__ p1,
    const float* __restrict__ grinv, float* out) {
    const size_t i = ((size_t)blockIdx.x * 256 + threadIdx.x) * 4;
    f32x4 a = *(const f32x4*)(p0 + i);
    f32x4 c = *(const f32x4*)(p1 + i);
    const int b = (int)(i >> 21);          // DV*NQ = 2^21
    const int q = (int)(i & (NQ - 1));
    f32x4 g = *(const f32x4*)(grinv + (size_t)b * NQ + q);
    f32x4 r = (a + c) * g;
    *(f32x4*)(out + i) = r;
}

// ---------------------------------------------------------------------------
extern "C" void kernel_launch(void* const* d_in, const int* in_sizes, int n_in,
                              void* d_out, int out_size, void* d_ws, size_t ws_size,
                              hipStream_t stream) {
    const float* qkey  = (const float*)d_in[0];
    // d_in[1] (qval) unused by the reference
    const int*   qmask = (const int*)d_in[2];
    const float* mkey  = (const float*)d_in[3];
    const float* mval  = (const float*)d_in[4];
    const int*   mmask = (const int*)d_in[5];
    float* out = (float*)d_out;

    char* ws = (char*)d_ws;
    size_t off = 0;
    const size_t QS  = (size_t)BATCH * NQ * DK * 2;          // 2 MB each
    const size_t KS2 = (size_t)BATCH * NM * DK * 2;          // 4 MB each (swizzled)
    const size_t VS  = (size_t)BATCH * NT * 2 * VTILE * 2;   // 16 MB
    const size_t OS  = (size_t)BATCH * DV * NQ * 4;          // 16.8 MB
    ushort_t* Qhi = (ushort_t*)(ws + off); off += QS;
    ushort_t* Qlo = (ushort_t*)(ws + off); off += QS;
    ushort_t* Khi = (ushort_t*)(ws + off); off += KS2;
    ushort_t* Klo = (ushort_t*)(ws + off); off += KS2;
    ushort_t* Vc  = (ushort_t*)(ws + off); off += VS;
    float* part1  = (float*)(ws + off); off += OS;           // chunk-1 partial
    float* mpart  = (float*)(ws + off); off += (size_t)BATCH * 4 * NQ * 4;
    float* lpart  = (float*)(ws + off); off += (size_t)BATCH * 4 * NQ * 4;
    float* gmaxb  = (float*)(ws + off); off += (size_t)BATCH * NQ * 4;
    float* grinv  = (float*)(ws + off); off += (size_t)BATCH * NQ * 4;
    int* cidx     = (int*)(ws + off); off += (size_t)BATCH * NM * 4;
    int* cpos     = (int*)(ws + off); off += (size_t)BATCH * NM * 4;
    int* cnts     = (int*)(ws + off); off += 64;
    int* qflags   = (int*)(ws + off); off += 64;

    scan_kernel<<<BATCH, 1024, 0, stream>>>(qmask, mmask, cidx, cpos, cnts, qflags);

    dim3 gq(NQ / 32, DK / 32, BATCH);
    prep_q_kernel<<<gq, 256, 0, stream>>>(qkey, Qhi, Qlo);
    dim3 gk(NM / 32, DK / 32, BATCH);
    prep_k_kernel<<<gk, 256, 0, stream>>>(mkey, mmask, cpos, Khi, Klo);
    dim3 gv(NM / 64, DV / 64, BATCH);
    prep_v_kernel<<<gv, 256, 0, stream>>>(mval, cidx, cnts, Vc);

    stats_kernel<<<(NQ / 32) * 8, 256, 0, stream>>>(
        Qhi, Qlo, Khi, Klo, cnts, mpart, lpart);
    finalize_kernel<<<(BATCH * NQ) / 256, 256, 0, stream>>>(
        mpart, lpart, cnts, qflags, qmask, gmaxb, grinv);

    pv_kernel<<<(NQ / 32) * 8, 256, 0, stream>>>(
        Qhi, Qlo, Khi, Klo, Vc, cnts, gmaxb, out, part1);

    combine_kernel<<<(int)((size_t)BATCH * DV * NQ / 1024), 256, 0, stream>>>(
        out, part1, grinv, out);
}